// Round 1
// baseline (408.466 us; speedup 1.0000x reference)
//
#include <hip/hip_runtime.h>
#include <hip/hip_bf16.h>

#define NN 50000
#define NE 800000

__device__ __forceinline__ float silu_f(float x) {
    return x * (1.0f / (1.0f + __expf(-x)));
}

// ---------------------------------------------------------------------------
// K1: per-edge weight MLP.  s_out[m][e] = edge_sh[e][m] * (silu(attr@W1+b1)@W2+b2)[m]
// thread-per-edge; attr tile staged in LDS (coalesced), s stored transposed.
// ---------------------------------------------------------------------------
__global__ __launch_bounds__(256) void k_edge_mlp(
    const float* __restrict__ edge_attr,   // [NE][32]
    const float* __restrict__ edge_sh,     // [NE][9]
    const float* __restrict__ W1,          // [32][64]
    const float* __restrict__ b1,          // [64]
    const float* __restrict__ W2,          // [64][9]
    const float* __restrict__ b2,          // [9]
    float* __restrict__ s_out)             // [9][NE]  (transposed)
{
    __shared__ float sAttr[256 * 36];      // pad 32 -> 36 (16B-aligned rows, conflict-light)
    const int t  = threadIdx.x;
    const int e0 = blockIdx.x * 256;

    const float* ga = edge_attr + (size_t)e0 * 32;
    #pragma unroll
    for (int k = 0; k < 32; ++k) {
        int i = k * 256 + t;
        sAttr[(i >> 5) * 36 + (i & 31)] = ga[i];
    }
    __syncthreads();

    float a[32];
    #pragma unroll
    for (int q = 0; q < 8; ++q) {
        float4 v = *(const float4*)&sAttr[t * 36 + q * 4];
        a[4*q+0] = v.x; a[4*q+1] = v.y; a[4*q+2] = v.z; a[4*q+3] = v.w;
    }

    float hid[64];
    #pragma unroll
    for (int h = 0; h < 64; ++h) hid[h] = b1[h];
    for (int d = 0; d < 32; ++d) {
        const float ad = a[d];
        const float* wr = W1 + d * 64;     // uniform row -> scalar-cached
        #pragma unroll
        for (int h = 0; h < 64; ++h) hid[h] += ad * wr[h];
    }

    float w[9];
    #pragma unroll
    for (int m = 0; m < 9; ++m) w[m] = b2[m];
    for (int h = 0; h < 64; ++h) {
        const float hv = silu_f(hid[h]);
        const float* w2r = W2 + h * 9;
        #pragma unroll
        for (int m = 0; m < 9; ++m) w[m] += hv * w2r[m];
    }

    const size_t e = (size_t)e0 + t;
    const float* sh = edge_sh + e * 9;
    #pragma unroll
    for (int m = 0; m < 9; ++m)
        s_out[(size_t)m * NE + e] = sh[m] * w[m];
}

// ---------------------------------------------------------------------------
// K2: U[n, m*64+g] = sum_f feat[n,f] * W_tp[f, m*64+g]
// GEMM [NN,64] x [64,576], 64x64 output tiles, K=64; U stored bf16.
// ---------------------------------------------------------------------------
__global__ __launch_bounds__(256) void k_u_gemm(
    const float* __restrict__ feat,        // [NN][64]
    const float* __restrict__ Wtp,         // [64][576]
    __hip_bfloat16* __restrict__ U)        // [NN][576] bf16
{
    __shared__ float sF[64 * 68];
    __shared__ float sW[64 * 68];
    const int t  = threadIdx.x;
    const int j0 = blockIdx.x * 64;
    const int n0 = blockIdx.y * 64;

    #pragma unroll
    for (int k = 0; k < 16; ++k) {
        int i = k * 256 + t;
        int r = i >> 6, c = i & 63;
        int n = n0 + r;
        sF[r * 68 + c] = (n < NN) ? feat[(size_t)n * 64 + c] : 0.f;
        sW[r * 68 + c] = Wtp[(size_t)r * 576 + j0 + c];
    }
    __syncthreads();

    const int tx = t & 15, ty = t >> 4;
    float acc[4][4] = {};
    for (int f = 0; f < 64; ++f) {
        float4 bq = *(const float4*)&sW[f * 68 + tx * 4];
        #pragma unroll
        for (int i = 0; i < 4; ++i) {
            float av = sF[(ty * 4 + i) * 68 + f];
            acc[i][0] += av * bq.x;
            acc[i][1] += av * bq.y;
            acc[i][2] += av * bq.z;
            acc[i][3] += av * bq.w;
        }
    }

    #pragma unroll
    for (int i = 0; i < 4; ++i) {
        int n = n0 + ty * 4 + i;
        if (n < NN) {
            __hip_bfloat16* ur = U + (size_t)n * 576 + j0 + tx * 4;
            #pragma unroll
            for (int j = 0; j < 4; ++j) ur[j] = __float2bfloat16(acc[i][j]);
        }
    }
}

// ---------------------------------------------------------------------------
// K3: per-edge combine + scatter.  One wave per edge, lane = output feature g.
// msg[g] = sum_m s[m][e] * U[src][m*64+g];  atomicAdd into agg[dst][g] * 0.25
// ---------------------------------------------------------------------------
__global__ __launch_bounds__(256) void k_combine(
    const int* __restrict__ ei,            // [2][NE]
    const float* __restrict__ s,           // [9][NE]
    const __hip_bfloat16* __restrict__ U,  // [NN][576]
    float* __restrict__ agg)               // [NN][64]  (= d_out)
{
    const int wid  = (blockIdx.x * 256 + threadIdx.x) >> 6;  // edge id
    const int lane = threadIdx.x & 63;
    const int src = ei[wid];
    const int dst = ei[NE + wid];
    const __hip_bfloat16* ur = U + (size_t)src * 576 + lane;
    float acc = 0.f;
    #pragma unroll
    for (int m = 0; m < 9; ++m)
        acc += s[(size_t)m * NE + wid] * __bfloat162float(ur[(size_t)m * 64]);
    atomicAdd(agg + (size_t)dst * 64 + lane, acc * 0.25f);   // 1/sqrt(16)
}

// ---------------------------------------------------------------------------
// K4: FiLM, in-place on d_out.  One wave per node, lane = feature g.
// hid[h] = silu(c*Wn1[h]+bn1[h]);  gamma/beta via shuffle-broadcast dot.
// ---------------------------------------------------------------------------
__global__ __launch_bounds__(256) void k_film(
    const float* __restrict__ c_noise,     // [NN]
    const float* __restrict__ Wn1,         // [64]
    const float* __restrict__ bn1,         // [64]
    const float* __restrict__ Wn2,         // [64][128]
    const float* __restrict__ bn2,         // [128]
    float* __restrict__ out)               // [NN][64]
{
    const int n    = (blockIdx.x * 256 + threadIdx.x) >> 6;
    const int lane = threadIdx.x & 63;
    const float c  = c_noise[n];
    const float hid = silu_f(c * Wn1[lane] + bn1[lane]);
    float g = bn2[lane];
    float b = bn2[64 + lane];
    for (int h = 0; h < 64; ++h) {
        const float hv = __shfl(hid, h, 64);
        g += hv * Wn2[h * 128 + lane];
        b += hv * Wn2[h * 128 + 64 + lane];
    }
    const size_t i = (size_t)n * 64 + lane;
    out[i] = out[i] * (1.0f + g) + b;
}

// ---------------------------------------------------------------------------
extern "C" void kernel_launch(void* const* d_in, const int* in_sizes, int n_in,
                              void* d_out, int out_size, void* d_ws, size_t ws_size,
                              hipStream_t stream) {
    const float* features  = (const float*)d_in[0];   // [NN][64]
    const int*   edge_index= (const int*)  d_in[1];   // [2][NE]
    const float* edge_attr = (const float*)d_in[2];   // [NE][32]
    const float* edge_sh   = (const float*)d_in[3];   // [NE][9]
    const float* c_noise   = (const float*)d_in[4];   // [NN]
    const float* W1        = (const float*)d_in[5];
    const float* b1        = (const float*)d_in[6];
    const float* W2        = (const float*)d_in[7];
    const float* b2        = (const float*)d_in[8];
    const float* W_tp      = (const float*)d_in[9];   // [64][576]
    const float* Wn1       = (const float*)d_in[10];
    const float* bn1       = (const float*)d_in[11];
    const float* Wn2       = (const float*)d_in[12];
    const float* bn2       = (const float*)d_in[13];
    float* out = (float*)d_out;

    char* ws = (char*)d_ws;
    float* s_buf = (float*)ws;                                  // [9][NE] f32 = 28.8 MB
    size_t s_bytes = (size_t)9 * NE * 4;                        // 28,800,000 (256-aligned)
    __hip_bfloat16* U = (__hip_bfloat16*)(ws + s_bytes);        // [NN][576] bf16 = 57.6 MB

    // zero the accumulator (d_out)
    hipMemsetAsync(d_out, 0, (size_t)NN * 64 * sizeof(float), stream);

    // K1: edge MLP -> s
    k_edge_mlp<<<NE / 256, 256, 0, stream>>>(edge_attr, edge_sh, W1, b1, W2, b2, s_buf);

    // K2: U = feat @ W_tp
    k_u_gemm<<<dim3(9, (NN + 63) / 64), 256, 0, stream>>>(features, W_tp, U);

    // K3: combine + scatter (wave per edge)
    k_combine<<<(NE * 64) / 256, 256, 0, stream>>>(edge_index, s_buf, U, out);

    // K4: FiLM in-place
    k_film<<<(NN * 64) / 256, 256, 0, stream>>>(c_noise, Wn1, bn1, Wn2, bn2, out);
}

// Round 2
// 407.310 us; speedup vs baseline: 1.0028x; 1.0028x over previous
//
#include <hip/hip_runtime.h>
#include <hip/hip_bf16.h>

#define NN 50000
#define NE 800000

typedef unsigned int u32;
typedef unsigned short u16;

__device__ __forceinline__ float silu_f(float x) {
    return x * (1.0f / (1.0f + __expf(-x)));
}
__device__ __forceinline__ float bf2f(u16 u) {
    return __uint_as_float(((u32)u) << 16);
}
__device__ __forceinline__ u16 f2bf(float f) {
    u32 x = __float_as_uint(f);
    return (u16)((x + 0x7fffu + ((x >> 16) & 1u)) >> 16);   // RNE
}

// ---------------------------------------------------------------------------
// Sort-by-dst machinery: histogram -> 2-level exclusive scan -> scatter ranks
// ---------------------------------------------------------------------------
__global__ __launch_bounds__(256) void k_hist(const int* __restrict__ ei, u32* __restrict__ cnt) {
    int e = blockIdx.x * 256 + threadIdx.x;
    atomicAdd(&cnt[ei[NE + e]], 1u);
}

__global__ __launch_bounds__(256) void k_scan_a(const u32* __restrict__ cnt, u32* __restrict__ part) {
    __shared__ u32 sb[256];
    int t = threadIdx.x, i = blockIdx.x * 256 + t;
    u32 v = (i < NN) ? cnt[i] : 0u;
    sb[t] = v; __syncthreads();
    for (int off = 128; off > 0; off >>= 1) { if (t < off) sb[t] += sb[t + off]; __syncthreads(); }
    if (t == 0) part[blockIdx.x] = sb[0];
}

__global__ __launch_bounds__(256) void k_scan_b(u32* __restrict__ part, int nparts) {
    __shared__ u32 sb[256];
    int t = threadIdx.x;
    u32 v = (t < nparts) ? part[t] : 0u;
    sb[t] = v; __syncthreads();
    for (int off = 1; off < 256; off <<= 1) {
        u32 x = (t >= off) ? sb[t - off] : 0u; __syncthreads();
        sb[t] += x; __syncthreads();
    }
    if (t < nparts) part[t] = sb[t] - v;          // exclusive
}

__global__ __launch_bounds__(256) void k_scan_c(const u32* __restrict__ cnt, const u32* __restrict__ part,
                                                u32* __restrict__ row, u32* __restrict__ rowcur) {
    __shared__ u32 sb[256];
    int t = threadIdx.x, i = blockIdx.x * 256 + t;
    u32 v = (i < NN) ? cnt[i] : 0u;
    sb[t] = v; __syncthreads();
    for (int off = 1; off < 256; off <<= 1) {
        u32 x = (t >= off) ? sb[t - off] : 0u; __syncthreads();
        sb[t] += x; __syncthreads();
    }
    if (i < NN) {
        u32 ex = part[blockIdx.x] + sb[t] - v;
        row[i] = ex; rowcur[i] = ex;
    }
    if (i == 0) row[NN] = NE;
}

__global__ __launch_bounds__(256) void k_scatter(const int* __restrict__ ei, u32* __restrict__ rowcur,
                                                 u32* __restrict__ rank, u32* __restrict__ ssrc) {
    int e = blockIdx.x * 256 + threadIdx.x;
    int d = ei[NE + e];
    u32 pos = atomicAdd(&rowcur[d], 1u);
    rank[e] = pos;
    ssrc[pos] = (u32)ei[e];
}

// ---------------------------------------------------------------------------
// K1: per-edge weight MLP; writes s (bf16, padded to 12) at sorted position.
// ---------------------------------------------------------------------------
__global__ __launch_bounds__(256) void k_edge_mlp(
    const float* __restrict__ edge_attr,   // [NE][32]
    const float* __restrict__ edge_sh,     // [NE][9]
    const float* __restrict__ W1, const float* __restrict__ b1,
    const float* __restrict__ W2, const float* __restrict__ b2,
    const u32* __restrict__ rank,
    u16* __restrict__ s_sorted)            // [NE][12] bf16 at rank[e]
{
    __shared__ float sAttr[256 * 36];
    const int t  = threadIdx.x;
    const int e0 = blockIdx.x * 256;

    const float* ga = edge_attr + (size_t)e0 * 32;
    #pragma unroll
    for (int k = 0; k < 32; ++k) {
        int i = k * 256 + t;
        sAttr[(i >> 5) * 36 + (i & 31)] = ga[i];
    }
    __syncthreads();

    float a[32];
    #pragma unroll
    for (int q = 0; q < 8; ++q) {
        float4 v = *(const float4*)&sAttr[t * 36 + q * 4];
        a[4*q+0] = v.x; a[4*q+1] = v.y; a[4*q+2] = v.z; a[4*q+3] = v.w;
    }

    float hid[64];
    #pragma unroll
    for (int h = 0; h < 64; ++h) hid[h] = b1[h];
    for (int d = 0; d < 32; ++d) {
        const float ad = a[d];
        const float* wr = W1 + d * 64;
        #pragma unroll
        for (int h = 0; h < 64; ++h) hid[h] += ad * wr[h];
    }

    float w[9];
    #pragma unroll
    for (int m = 0; m < 9; ++m) w[m] = b2[m];
    for (int h = 0; h < 64; ++h) {
        const float hv = silu_f(hid[h]);
        const float* w2r = W2 + h * 9;
        #pragma unroll
        for (int m = 0; m < 9; ++m) w[m] += hv * w2r[m];
    }

    const size_t e = (size_t)e0 + t;
    const float* sh = edge_sh + e * 9;
    u16 sw[12];
    #pragma unroll
    for (int m = 0; m < 9; ++m) sw[m] = f2bf(sh[m] * w[m]);
    sw[9] = sw[10] = sw[11] = 0;

    u16* dp = s_sorted + (size_t)rank[e] * 12;
    ushort4 v0{sw[0], sw[1], sw[2],  sw[3]};
    ushort4 v1{sw[4], sw[5], sw[6],  sw[7]};
    ushort4 v2{sw[8], sw[9], sw[10], sw[11]};
    *(ushort4*)(dp + 0) = v0;
    *(ushort4*)(dp + 4) = v1;
    *(ushort4*)(dp + 8) = v2;
}

// ---------------------------------------------------------------------------
// K2: U[n, m*64+g] = sum_f feat[n,f] * W_tp[f, m*64+g]   (bf16 out)
// ---------------------------------------------------------------------------
__global__ __launch_bounds__(256) void k_u_gemm(
    const float* __restrict__ feat, const float* __restrict__ Wtp,
    u16* __restrict__ U)
{
    __shared__ float sF[64 * 68];
    __shared__ float sW[64 * 68];
    const int t  = threadIdx.x;
    const int j0 = blockIdx.x * 64;
    const int n0 = blockIdx.y * 64;

    #pragma unroll
    for (int k = 0; k < 16; ++k) {
        int i = k * 256 + t;
        int r = i >> 6, c = i & 63;
        int n = n0 + r;
        sF[r * 68 + c] = (n < NN) ? feat[(size_t)n * 64 + c] : 0.f;
        sW[r * 68 + c] = Wtp[(size_t)r * 576 + j0 + c];
    }
    __syncthreads();

    const int tx = t & 15, ty = t >> 4;
    float acc[4][4] = {};
    for (int f = 0; f < 64; ++f) {
        float4 bq = *(const float4*)&sW[f * 68 + tx * 4];
        #pragma unroll
        for (int i = 0; i < 4; ++i) {
            float av = sF[(ty * 4 + i) * 68 + f];
            acc[i][0] += av * bq.x;
            acc[i][1] += av * bq.y;
            acc[i][2] += av * bq.z;
            acc[i][3] += av * bq.w;
        }
    }

    #pragma unroll
    for (int i = 0; i < 4; ++i) {
        int n = n0 + ty * 4 + i;
        if (n < NN) {
            u16* ur = U + (size_t)n * 576 + j0 + tx * 4;
            #pragma unroll
            for (int j = 0; j < 4; ++j) ur[j] = f2bf(acc[i][j]);
        }
    }
}

// ---------------------------------------------------------------------------
// K3: gather-reduce per node (wave per node, lane = out feature) + fused FiLM.
// No atomics: edges are dst-sorted; acc in a register, one store per node.
// ---------------------------------------------------------------------------
__global__ __launch_bounds__(256) void k_combine_film(
    const u32* __restrict__ row, const u32* __restrict__ ssrc,
    const u16* __restrict__ s_sorted, const u16* __restrict__ U,
    const float* __restrict__ c_noise,
    const float* __restrict__ Wn1, const float* __restrict__ bn1,
    const float* __restrict__ Wn2, const float* __restrict__ bn2,
    float* __restrict__ out)
{
    const int n    = blockIdx.x * 4 + (threadIdx.x >> 6);
    const int lane = threadIdx.x & 63;
    if (n >= NN) return;

    // FiLM hidden (independent of edge loop; its loads issue early)
    const float c   = c_noise[n];
    const float hid = silu_f(fmaf(c, Wn1[lane], bn1[lane]));

    const u32 p0 = row[n], p1 = row[n + 1];
    float acc = 0.f;
    for (u32 p = p0; p < p1; ++p) {
        const u32 src = ssrc[p];
        const u16* sp = s_sorted + (size_t)p * 12;
        const ushort4 sa = *(const ushort4*)(sp + 0);
        const ushort4 sb = *(const ushort4*)(sp + 4);
        const u16     s8 = sp[8];
        const u16* ur = U + (size_t)src * 576 + lane;
        float m0 = bf2f(ur[0*64]), m1 = bf2f(ur[1*64]), m2 = bf2f(ur[2*64]);
        float m3 = bf2f(ur[3*64]), m4 = bf2f(ur[4*64]), m5 = bf2f(ur[5*64]);
        float m6 = bf2f(ur[6*64]), m7 = bf2f(ur[7*64]), m8 = bf2f(ur[8*64]);
        acc = fmaf(bf2f(sa.x), m0, acc);
        acc = fmaf(bf2f(sa.y), m1, acc);
        acc = fmaf(bf2f(sa.z), m2, acc);
        acc = fmaf(bf2f(sa.w), m3, acc);
        acc = fmaf(bf2f(sb.x), m4, acc);
        acc = fmaf(bf2f(sb.y), m5, acc);
        acc = fmaf(bf2f(sb.z), m6, acc);
        acc = fmaf(bf2f(sb.w), m7, acc);
        acc = fmaf(bf2f(s8),   m8, acc);
    }
    acc *= 0.25f;                                   // 1/sqrt(AVG_DEG=16)

    // FiLM gamma/beta via shuffle-broadcast dot over hidden
    float g = bn2[lane], b = bn2[64 + lane];
    for (int h = 0; h < 64; ++h) {
        const float hv = __shfl(hid, h, 64);
        g = fmaf(hv, Wn2[h * 128 + lane],      g);
        b = fmaf(hv, Wn2[h * 128 + 64 + lane], b);
    }
    out[(size_t)n * 64 + lane] = fmaf(acc, 1.f + g, b);
}

// ---------------------------------------------------------------------------
extern "C" void kernel_launch(void* const* d_in, const int* in_sizes, int n_in,
                              void* d_out, int out_size, void* d_ws, size_t ws_size,
                              hipStream_t stream) {
    const float* features   = (const float*)d_in[0];
    const int*   edge_index = (const int*)  d_in[1];
    const float* edge_attr  = (const float*)d_in[2];
    const float* edge_sh    = (const float*)d_in[3];
    const float* c_noise    = (const float*)d_in[4];
    const float* W1  = (const float*)d_in[5];
    const float* b1  = (const float*)d_in[6];
    const float* W2  = (const float*)d_in[7];
    const float* b2  = (const float*)d_in[8];
    const float* Wtp = (const float*)d_in[9];
    const float* Wn1 = (const float*)d_in[10];
    const float* bn1 = (const float*)d_in[11];
    const float* Wn2 = (const float*)d_in[12];
    const float* bn2 = (const float*)d_in[13];
    float* out = (float*)d_out;

    char* ws = (char*)d_ws;
    u16* U        = (u16*)(ws);                    // 57,600,000 B
    u16* s_sorted = (u16*)(ws + 57600000);         // 19,200,000 B
    u32* row      = (u32*)(ws + 76800000);         //    200,064 B
    u32* rowcur   = (u32*)(ws + 77000064);         //    200,064 B
    u32* cnt      = (u32*)(ws + 77200128);         //    200,064 B
    u32* part     = (u32*)(ws + 77400192);         //      1,024 B
    u32* rank     = (u32*)(ws + 77401216);         //  3,200,000 B
    u32* ssrc     = (u32*)(ws + 80601216);         //  3,200,000 B  (end 83.8 MB)

    const int nparts = (NN + 255) / 256;           // 196

    hipMemsetAsync(cnt, 0, (size_t)NN * 4, stream);
    k_hist   <<<NE / 256, 256, 0, stream>>>(edge_index, cnt);
    k_scan_a <<<nparts, 256, 0, stream>>>(cnt, part);
    k_scan_b <<<1, 256, 0, stream>>>(part, nparts);
    k_scan_c <<<nparts, 256, 0, stream>>>(cnt, part, row, rowcur);
    k_scatter<<<NE / 256, 256, 0, stream>>>(edge_index, rowcur, rank, ssrc);

    k_edge_mlp<<<NE / 256, 256, 0, stream>>>(edge_attr, edge_sh, W1, b1, W2, b2, rank, s_sorted);
    k_u_gemm  <<<dim3(9, (NN + 63) / 64), 256, 0, stream>>>(features, Wtp, U);

    k_combine_film<<<(NN + 3) / 4, 256, 0, stream>>>(row, ssrc, s_sorted, U,
                                                     c_noise, Wn1, bn1, Wn2, bn2, out);
}